// Round 14
// baseline (463.059 us; speedup 1.0000x reference)
//
#include <hip/hip_runtime.h>
#include <hip/hip_bf16.h>

#define CDIM 128
#define SCAN_CHUNK 2048   // elements per scan block (256 thr x 8)

typedef __attribute__((ext_vector_type(4))) float f32x4;
typedef __attribute__((ext_vector_type(8))) short bf16x8;
typedef __attribute__((ext_vector_type(4))) short bf16x4;

// RNE f32->bf16
__device__ __forceinline__ short f2bf(float f) {
    unsigned u = __float_as_uint(f);
    u += 0x7FFFu + ((u >> 16) & 1u);
    return (short)(u >> 16);
}

// ---------------- CSR build ----------------

__global__ __launch_bounds__(256) void zero_ints(int* __restrict__ p, int n) {
    int i = blockIdx.x * 256 + threadIdx.x;
    for (; i < n; i += gridDim.x * 256) p[i] = 0;
}

// histogram + per-edge rank within destination (atomicAdd return value)
__global__ __launch_bounds__(256) void hist_rank(
    const int* __restrict__ c1, int nnz1, const int* __restrict__ c2, int nnz2,
    int n1, int* __restrict__ counts, int* __restrict__ rank)
{
    const int gtid = blockIdx.x * 256 + threadIdx.x;
    const int gstride = gridDim.x * 256;
    for (int e = gtid; e < nnz1; e += gstride)
        rank[e] = atomicAdd(&counts[c1[e]], 1);
    for (int e = gtid; e < nnz2; e += gstride)
        rank[nnz1 + e] = atomicAdd(&counts[n1 + c2[e]], 1);
}

// per-chunk exclusive scan; chunk total -> bsums[chunk]
__global__ __launch_bounds__(256) void scan_chunks(const int* __restrict__ in, int* __restrict__ out,
                                                   int* __restrict__ bsums, int n) {
    __shared__ int wtot[4];
    const int t = threadIdx.x;
    const int base = blockIdx.x * SCAN_CHUNK + t * 8;
    int v[8]; int s = 0;
#pragma unroll
    for (int j = 0; j < 8; ++j) {
        int c = (base + j < n) ? in[base + j] : 0;
        v[j] = s; s += c;
    }
    const int lane = t & 63, w = t >> 6;
    int inc = s;
#pragma unroll
    for (int d = 1; d < 64; d <<= 1) {
        int o = __shfl_up(inc, d);
        if (lane >= d) inc += o;
    }
    if (lane == 63) wtot[w] = inc;
    __syncthreads();
    int off = inc - s;
    for (int i = 0; i < w; ++i) off += wtot[i];
#pragma unroll
    for (int j = 0; j < 8; ++j)
        if (base + j < n) out[base + j] = v[j] + off;
    if (t == 255) bsums[blockIdx.x] = off + s;
}

// block b: add sum(bsums[0..b)) to its chunk of row_ptr; set row_ptr[N]
__global__ __launch_bounds__(256) void scan_finalize(int* __restrict__ row_ptr,
                                                     const int* __restrict__ bsums,
                                                     int n, int nnzT) {
    __shared__ int wsum[4];
    const int t = threadIdx.x, lane = t & 63, w = t >> 6;
    int s = 0;
    for (int i = t; i < (int)blockIdx.x; i += 256) s += bsums[i];
#pragma unroll
    for (int d = 1; d < 64; d <<= 1) s += __shfl_xor(s, d);
    if (lane == 0) wsum[w] = s;
    __syncthreads();
    const int off = wsum[0] + wsum[1] + wsum[2] + wsum[3];
    const int base = blockIdx.x * SCAN_CHUNK + t * 8;
#pragma unroll
    for (int j = 0; j < 8; ++j) {
        const int i = base + j;
        if (i < n) row_ptr[i] += off;
    }
    if (blockIdx.x == 0 && t == 0) row_ptr[n] = nnzT;
}

// ---------------- balanced co-dispatch: scatter (odd blocks) || GEMM (even blocks) ----------------
// Both roles get 2048 blocks (their standalone-optimal grids). Scatter is
// latency-bound, gemm BW/MFMA-bound -> complementary resources overlap.
__global__ __launch_bounds__(256) void scatter_gemm(
    const int* __restrict__ r1, const int* __restrict__ c1, const float* __restrict__ v1, int nnz1,
    const int* __restrict__ r2, const int* __restrict__ c2, const float* __restrict__ v2, int nnz2,
    int n1, const int* __restrict__ row_ptr, const int* __restrict__ rank,
    unsigned long long* __restrict__ csr,
    const float* __restrict__ x0, const float* __restrict__ W1, short* __restrict__ h0, int t0,
    const float* __restrict__ x1, const float* __restrict__ W2, short* __restrict__ h1, int t1,
    int g0)
{
    __shared__ short Bfrag[4][8][64][8];   // [kk][nb][lane][j] = 32 KB, lane-linear 16B slots

    if (blockIdx.x & 1) {
        // ---- scatter role (2048 virtual blocks) ----
        const int gtid = (blockIdx.x >> 1) * 256 + threadIdx.x;
        const int gstride = (gridDim.x >> 1) * 256;
        for (int e = gtid; e < nnz1; e += gstride) {
            int p = row_ptr[c1[e]] + rank[e];
            csr[p] = ((unsigned long long)__float_as_uint(__builtin_nontemporal_load(&v1[e])) << 32)
                     | (unsigned)__builtin_nontemporal_load(&r1[e]);
        }
        for (int e = gtid; e < nnz2; e += gstride) {
            int p = row_ptr[n1 + c2[e]] + rank[nnz1 + e];
            csr[p] = ((unsigned long long)__float_as_uint(__builtin_nontemporal_load(&v2[e])) << 32)
                     | (unsigned)__builtin_nontemporal_load(&r2[e]);
        }
        return;
    }

    // ---- gemm role (2048 virtual blocks) ----
    const int gb = blockIdx.x >> 1;
    const int ngemm = gridDim.x >> 1;
    const float* __restrict__ x; const float* __restrict__ W; short* __restrict__ h;
    int ntiles, bidx, nblk;
    if (gb < g0) { x = x0; W = W1; h = h0; ntiles = t0; bidx = gb;      nblk = g0; }
    else         { x = x1; W = W2; h = h1; ntiles = t1; bidx = gb - g0; nblk = ngemm - g0; }

    for (int slot = threadIdx.x; slot < 2048; slot += 256) {
        const int lane = slot & 63, nb = (slot >> 6) & 7, kk = slot >> 9;
        const int n  = nb * 16 + (lane & 15);
        const int k0 = kk * 32 + (lane >> 4) * 8;
        union { bf16x8 v; short s[8]; } f;
#pragma unroll
        for (int j = 0; j < 8; ++j) f.s[j] = f2bf(W[(k0 + j) * CDIM + n]);
        *(bf16x8*)&Bfrag[kk][nb][lane][0] = f.v;
    }
    __syncthreads();

    const int lane = threadIdx.x & 63;
    const int wid  = threadIdx.x >> 6;
    const int l15  = lane & 15;
    const int l4   = lane >> 4;

    for (int tile = bidx * 4 + wid; tile < ntiles; tile += nblk * 4) {
        const int rbase = tile << 4;
        const int row = rbase + l15;
        const float* __restrict__ xr = x + (long)row * CDIM + (l4 << 3);

        union { bf16x8 v; short s[8]; } X[4];
#pragma unroll
        for (int kk = 0; kk < 4; ++kk) {
            f32x4 a0 = __builtin_nontemporal_load((const f32x4*)(xr + kk * 32));
            f32x4 a1 = __builtin_nontemporal_load((const f32x4*)(xr + kk * 32 + 4));
#pragma unroll
            for (int j = 0; j < 4; ++j) { X[kk].s[j] = f2bf(a0[j]); X[kk].s[4 + j] = f2bf(a1[j]); }
        }

        f32x4 c[8];
#pragma unroll
        for (int nb = 0; nb < 8; ++nb) c[nb] = (f32x4){0.f, 0.f, 0.f, 0.f};
#pragma unroll
        for (int kk = 0; kk < 4; ++kk)
#pragma unroll
            for (int nb = 0; nb < 8; ++nb)
                c[nb] = __builtin_amdgcn_mfma_f32_16x16x32_bf16(
                            *(const bf16x8*)&Bfrag[kk][nb][lane][0], X[kk].v, c[nb], 0, 0, 0);

        short* __restrict__ hr = h + (long)row * CDIM + (l4 << 2);
#pragma unroll
        for (int nb = 0; nb < 8; ++nb) {
            bf16x4 p;
#pragma unroll
            for (int ri = 0; ri < 4; ++ri) p[ri] = f2bf(c[nb][ri]);
            *(bf16x4*)(hr + (nb << 4)) = p;
        }
    }
}

// ---------------- gather-aggregate-sigmoid ----------------
// 16 lanes per dest row. Lane t16 fetches csr[beg+t16] (one load covers <=16
// edges). Batch-of-8: issue up to 8 h-row gathers back-to-back (all in flight
// concurrently), THEN fma -> ~1 latency exposure per wave for deg<=8 (99.9%).
__global__ __launch_bounds__(256) void agg_all(
    const short* __restrict__ h0, const short* __restrict__ h1,
    const int* __restrict__ row_ptr, const unsigned long long* __restrict__ csr,
    float* __restrict__ out, int n1, int nnzT)
{
    const int lane = threadIdx.x & 63;
    const int wid  = threadIdx.x >> 6;
    const int g    = lane >> 4;
    const int t16  = lane & 15;
    const int r = blockIdx.x * 16 + wid * 4 + g;
    const short* __restrict__ h = (r < n1) ? h0 : h1;   // n1 % 16 == 0 -> block-uniform
    const int beg = row_ptr[r];
    const int end = row_ptr[r + 1];
    const int deg = end - beg;

    int fi = beg + t16; if (fi > nnzT - 1) fi = nnzT - 1;
    const unsigned long long my = __builtin_nontemporal_load(&csr[fi]);

    const int m = deg < 16 ? deg : 16;
    const int gbase = g << 4;
    float acc[8] = {0.f, 0.f, 0.f, 0.f, 0.f, 0.f, 0.f, 0.f};

    bf16x8 hv[8]; float vv[8];
    // ---- batch 1: edges 0..7, loads issued back-to-back before any use ----
#pragma unroll
    for (int j = 0; j < 8; ++j) {
        if (j < m) {
            unsigned long long pv = __shfl(my, gbase + j);
            vv[j] = __uint_as_float((unsigned)(pv >> 32));
            hv[j] = *(const bf16x8*)(h + (long)(unsigned)(pv & 0xffffffffu) * CDIM + (t16 << 3));
        }
    }
#pragma unroll
    for (int j = 0; j < 8; ++j) {
        if (j < m) {
            union { bf16x8 v; unsigned u[4]; } H; H.v = hv[j];
#pragma unroll
            for (int d = 0; d < 4; ++d) {
                acc[2 * d]     += vv[j] * __uint_as_float(H.u[d] << 16);
                acc[2 * d + 1] += vv[j] * __uint_as_float(H.u[d] & 0xffff0000u);
            }
        }
    }
    // ---- batch 2: edges 8..15 (rare) ----
    if (__any(m > 8)) {
#pragma unroll
        for (int j = 8; j < 16; ++j) {
            if (j < m) {
                unsigned long long pv = __shfl(my, gbase + j);
                vv[j - 8] = __uint_as_float((unsigned)(pv >> 32));
                hv[j - 8] = *(const bf16x8*)(h + (long)(unsigned)(pv & 0xffffffffu) * CDIM + (t16 << 3));
            }
        }
#pragma unroll
        for (int j = 8; j < 16; ++j) {
            if (j < m) {
                union { bf16x8 v; unsigned u[4]; } H; H.v = hv[j - 8];
#pragma unroll
                for (int d = 0; d < 4; ++d) {
                    acc[2 * d]     += vv[j - 8] * __uint_as_float(H.u[d] << 16);
                    acc[2 * d + 1] += vv[j - 8] * __uint_as_float(H.u[d] & 0xffff0000u);
                }
            }
        }
    }
    // ---- serial tail for deg > 16 (statistically ~never) ----
    for (int i = beg + 16; i < end; ++i) {
        const unsigned long long pv = csr[i];
        const float val = __uint_as_float((unsigned)(pv >> 32));
        union { bf16x8 v; unsigned u[4]; } H;
        H.v = *(const bf16x8*)(h + (long)(unsigned)(pv & 0xffffffffu) * CDIM + (t16 << 3));
#pragma unroll
        for (int d = 0; d < 4; ++d) {
            acc[2 * d]     += val * __uint_as_float(H.u[d] << 16);
            acc[2 * d + 1] += val * __uint_as_float(H.u[d] & 0xffff0000u);
        }
    }

    f32x4 o0, o1;
#pragma unroll
    for (int j = 0; j < 4; ++j) {
        o0[j] = 1.0f / (1.0f + __expf(-acc[j]));
        o1[j] = 1.0f / (1.0f + __expf(-acc[4 + j]));
    }
    float* __restrict__ orow = out + (long)r * CDIM + (t16 << 3);
    __builtin_nontemporal_store(o0, (f32x4*)orow);
    __builtin_nontemporal_store(o1, (f32x4*)(orow + 4));
}

// ---------------- launch ----------------

extern "C" void kernel_launch(void* const* d_in, const int* in_sizes, int n_in,
                              void* d_out, int out_size, void* d_ws, size_t ws_size,
                              hipStream_t stream) {
    const float* x0 = (const float*)d_in[0];
    const float* x1 = (const float*)d_in[1];
    const float* W1 = (const float*)d_in[3];
    const float* W2 = (const float*)d_in[4];
    const int*   b1r = (const int*)d_in[5];
    const int*   b1c = (const int*)d_in[6];
    const float* b1v = (const float*)d_in[7];
    const int*   b2r = (const int*)d_in[8];
    const int*   b2c = (const int*)d_in[9];
    const float* b2v = (const float*)d_in[10];
    const int nnz1 = in_sizes[5];
    const int nnz2 = in_sizes[8];
    const int n0 = in_sizes[0] / CDIM;   // 100000
    const int n1 = in_sizes[1] / CDIM;   // 400000 (x1 rows = out1 rows)
    const int n2 = in_sizes[2] / CDIM;   // 300000
    const int N  = n1 + n2;              // combined dest space
    const int nnzT = nnz1 + nnz2;

    // workspace carve-up (ints unless noted)
    int* counts  = (int*)d_ws;                 // N
    int* row_ptr = counts + N;                 // N+1
    int* rank    = row_ptr + N + 1;            // nnzT
    int* bsums   = rank + nnzT;                // 512
    size_t iofs = (size_t)2 * N + 1 + nnzT + 512;
    iofs = (iofs + 1) & ~(size_t)1;            // 8B align
    unsigned long long* csr = (unsigned long long*)((int*)d_ws + iofs);  // nnzT (8B each)
    short* h0 = (short*)(csr + nnzT);          // n0*128 bf16
    short* h1 = h0 + (size_t)n0 * CDIM;        // n1*128 bf16

    float* out = (float*)d_out;                // rows [0, N) x 128

    const int nchunks = (N + SCAN_CHUNK - 1) / SCAN_CHUNK;  // 342 <= 512

    zero_ints<<<1024, 256, 0, stream>>>(counts, N);
    hist_rank<<<2048, 256, 0, stream>>>(b1c, nnz1, b2c, nnz2, n1, counts, rank);
    scan_chunks<<<nchunks, 256, 0, stream>>>(counts, row_ptr, bsums, N);
    scan_finalize<<<nchunks, 256, 0, stream>>>(row_ptr, bsums, N, nnzT);

    const int t0 = n0 >> 4, t1 = n1 >> 4;
    scatter_gemm<<<4096, 256, 0, stream>>>(
        b1r, b1c, b1v, nnz1, b2r, b2c, b2v, nnz2, n1, row_ptr, rank, csr,
        x0, W1, h0, t0, x1, W2, h1, t1, 416);

    agg_all<<<N >> 4, 256, 0, stream>>>(h0, h1, row_ptr, csr, out, n1, nnzT);
}

// Round 15
// 388.995 us; speedup vs baseline: 1.1904x; 1.1904x over previous
//
#include <hip/hip_runtime.h>
#include <hip/hip_bf16.h>

#define CDIM 128
#define SCAN_CHUNK 2048   // elements per scan block (256 thr x 8)

typedef __attribute__((ext_vector_type(4))) float f32x4;
typedef __attribute__((ext_vector_type(8))) short bf16x8;
typedef __attribute__((ext_vector_type(4))) short bf16x4;

// RNE f32->bf16
__device__ __forceinline__ short f2bf(float f) {
    unsigned u = __float_as_uint(f);
    u += 0x7FFFu + ((u >> 16) & 1u);
    return (short)(u >> 16);
}

// ---------------- CSR build ----------------

__global__ __launch_bounds__(256) void zero_ints(int* __restrict__ p, int n) {
    int i = blockIdx.x * 256 + threadIdx.x;
    for (; i < n; i += gridDim.x * 256) p[i] = 0;
}

// histogram + per-edge rank within destination (atomicAdd return value)
__global__ __launch_bounds__(256) void hist_rank(
    const int* __restrict__ c1, int nnz1, const int* __restrict__ c2, int nnz2,
    int n1, int* __restrict__ counts, int* __restrict__ rank)
{
    const int gtid = blockIdx.x * 256 + threadIdx.x;
    const int gstride = gridDim.x * 256;
    for (int e = gtid; e < nnz1; e += gstride)
        rank[e] = atomicAdd(&counts[c1[e]], 1);
    for (int e = gtid; e < nnz2; e += gstride)
        rank[nnz1 + e] = atomicAdd(&counts[n1 + c2[e]], 1);
}

// per-chunk exclusive scan; chunk total -> bsums[chunk]
__global__ __launch_bounds__(256) void scan_chunks(const int* __restrict__ in, int* __restrict__ out,
                                                   int* __restrict__ bsums, int n) {
    __shared__ int wtot[4];
    const int t = threadIdx.x;
    const int base = blockIdx.x * SCAN_CHUNK + t * 8;
    int v[8]; int s = 0;
#pragma unroll
    for (int j = 0; j < 8; ++j) {
        int c = (base + j < n) ? in[base + j] : 0;
        v[j] = s; s += c;
    }
    const int lane = t & 63, w = t >> 6;
    int inc = s;
#pragma unroll
    for (int d = 1; d < 64; d <<= 1) {
        int o = __shfl_up(inc, d);
        if (lane >= d) inc += o;
    }
    if (lane == 63) wtot[w] = inc;
    __syncthreads();
    int off = inc - s;
    for (int i = 0; i < w; ++i) off += wtot[i];
#pragma unroll
    for (int j = 0; j < 8; ++j)
        if (base + j < n) out[base + j] = v[j] + off;
    if (t == 255) bsums[blockIdx.x] = off + s;
}

// block b: add sum(bsums[0..b)) to its chunk of row_ptr; set row_ptr[N]
__global__ __launch_bounds__(256) void scan_finalize(int* __restrict__ row_ptr,
                                                     const int* __restrict__ bsums,
                                                     int n, int nnzT) {
    __shared__ int wsum[4];
    const int t = threadIdx.x, lane = t & 63, w = t >> 6;
    int s = 0;
    for (int i = t; i < (int)blockIdx.x; i += 256) s += bsums[i];
#pragma unroll
    for (int d = 1; d < 64; d <<= 1) s += __shfl_xor(s, d);
    if (lane == 0) wsum[w] = s;
    __syncthreads();
    const int off = wsum[0] + wsum[1] + wsum[2] + wsum[3];
    const int base = blockIdx.x * SCAN_CHUNK + t * 8;
#pragma unroll
    for (int j = 0; j < 8; ++j) {
        const int i = base + j;
        if (i < n) row_ptr[i] += off;
    }
    if (blockIdx.x == 0 && t == 0) row_ptr[n] = nnzT;
}

// atomic-free scatter: pos = row_ptr[dest] + rank[e]
__global__ __launch_bounds__(256) void scatter_both(
    const int* __restrict__ r1, const int* __restrict__ c1, const float* __restrict__ v1, int nnz1,
    const int* __restrict__ r2, const int* __restrict__ c2, const float* __restrict__ v2, int nnz2,
    int n1, const int* __restrict__ row_ptr, const int* __restrict__ rank,
    unsigned long long* __restrict__ csr)
{
    const int gtid = blockIdx.x * 256 + threadIdx.x;
    const int gstride = gridDim.x * 256;
    for (int e = gtid; e < nnz1; e += gstride) {
        int p = row_ptr[c1[e]] + rank[e];
        csr[p] = ((unsigned long long)__float_as_uint(__builtin_nontemporal_load(&v1[e])) << 32)
                 | (unsigned)__builtin_nontemporal_load(&r1[e]);
    }
    for (int e = gtid; e < nnz2; e += gstride) {
        int p = row_ptr[n1 + c2[e]] + rank[nnz1 + e];
        csr[p] = ((unsigned long long)__float_as_uint(__builtin_nontemporal_load(&v2[e])) << 32)
                 | (unsigned)__builtin_nontemporal_load(&r2[e]);
    }
}

// ---------------- dense GEMM: h = bf16(x @ W), both inputs in one launch ----------------
// Cross-iteration prefetch: next tile's 8 NT x-loads issue BEFORE the current
// tile's convert/MFMA/store, so each wave exposes ~1 load latency total
// instead of one per iteration (~4).
__global__ __launch_bounds__(256) void gemm_all(
    const float* __restrict__ x0, const float* __restrict__ W1, short* __restrict__ h0, int t0,
    const float* __restrict__ x1, const float* __restrict__ W2, short* __restrict__ h1, int t1,
    int g0)
{
    const float* __restrict__ x; const float* __restrict__ W; short* __restrict__ h;
    int ntiles, bidx, nblk;
    if ((int)blockIdx.x < g0) { x = x0; W = W1; h = h0; ntiles = t0; bidx = blockIdx.x;       nblk = g0; }
    else                      { x = x1; W = W2; h = h1; ntiles = t1; bidx = blockIdx.x - g0; nblk = gridDim.x - g0; }

    __shared__ short Bfrag[4][8][64][8];   // [kk][nb][lane][j] = 32 KB, lane-linear 16B slots
    for (int slot = threadIdx.x; slot < 2048; slot += 256) {
        const int lane = slot & 63, nb = (slot >> 6) & 7, kk = slot >> 9;
        const int n  = nb * 16 + (lane & 15);
        const int k0 = kk * 32 + (lane >> 4) * 8;
        union { bf16x8 v; short s[8]; } f;
#pragma unroll
        for (int j = 0; j < 8; ++j) f.s[j] = f2bf(W[(k0 + j) * CDIM + n]);
        *(bf16x8*)&Bfrag[kk][nb][lane][0] = f.v;
    }
    __syncthreads();

    const int lane = threadIdx.x & 63;
    const int wid  = threadIdx.x >> 6;
    const int l15  = lane & 15;
    const int l4   = lane >> 4;
    const int stride = nblk * 4;

    int tile = bidx * 4 + wid;
    if (tile >= ntiles) return;

    f32x4 cur[8];
    {
        const float* __restrict__ p = x + (long)((tile << 4) + l15) * CDIM + (l4 << 3);
#pragma unroll
        for (int q = 0; q < 4; ++q) {
            cur[2 * q]     = __builtin_nontemporal_load((const f32x4*)(p + q * 32));
            cur[2 * q + 1] = __builtin_nontemporal_load((const f32x4*)(p + q * 32 + 4));
        }
    }

    for (;;) {
        const int nxt_tile = tile + stride;
        const bool has = nxt_tile < ntiles;
        f32x4 nxt[8];
        {
            const int lt = has ? nxt_tile : tile;   // dummy reload (cache-hot) on last iter
            const float* __restrict__ p = x + (long)((lt << 4) + l15) * CDIM + (l4 << 3);
#pragma unroll
            for (int q = 0; q < 4; ++q) {
                nxt[2 * q]     = __builtin_nontemporal_load((const f32x4*)(p + q * 32));
                nxt[2 * q + 1] = __builtin_nontemporal_load((const f32x4*)(p + q * 32 + 4));
            }
        }

        union { bf16x8 v; short s[8]; } X[4];
#pragma unroll
        for (int kk = 0; kk < 4; ++kk)
#pragma unroll
            for (int j = 0; j < 4; ++j) {
                X[kk].s[j]     = f2bf(cur[2 * kk][j]);
                X[kk].s[4 + j] = f2bf(cur[2 * kk + 1][j]);
            }

        f32x4 c[8];
#pragma unroll
        for (int nb = 0; nb < 8; ++nb) c[nb] = (f32x4){0.f, 0.f, 0.f, 0.f};
#pragma unroll
        for (int kk = 0; kk < 4; ++kk)
#pragma unroll
            for (int nb = 0; nb < 8; ++nb)
                c[nb] = __builtin_amdgcn_mfma_f32_16x16x32_bf16(
                            *(const bf16x8*)&Bfrag[kk][nb][lane][0], X[kk].v, c[nb], 0, 0, 0);

        short* __restrict__ hr = h + (long)((tile << 4) + l15) * CDIM + (l4 << 2);
#pragma unroll
        for (int nb = 0; nb < 8; ++nb) {
            bf16x4 p;
#pragma unroll
            for (int ri = 0; ri < 4; ++ri) p[ri] = f2bf(c[nb][ri]);
            *(bf16x4*)(hr + (nb << 4)) = p;
        }

        if (!has) break;
        tile = nxt_tile;
#pragma unroll
        for (int q = 0; q < 8; ++q) cur[q] = nxt[q];
    }
}

// ---------------- gather-aggregate-sigmoid ----------------
// 16 lanes per dest row. Lane t16 fetches csr[beg+t16] (one load covers <=16
// edges). Batch-of-8: issue up to 8 h-row gathers back-to-back (all in flight
// concurrently), THEN fma -> ~1 latency exposure per wave for deg<=8 (99.9%).
__global__ __launch_bounds__(256) void agg_all(
    const short* __restrict__ h0, const short* __restrict__ h1,
    const int* __restrict__ row_ptr, const unsigned long long* __restrict__ csr,
    float* __restrict__ out, int n1, int nnzT)
{
    const int lane = threadIdx.x & 63;
    const int wid  = threadIdx.x >> 6;
    const int g    = lane >> 4;
    const int t16  = lane & 15;
    const int r = blockIdx.x * 16 + wid * 4 + g;
    const short* __restrict__ h = (r < n1) ? h0 : h1;   // n1 % 16 == 0 -> block-uniform
    const int beg = row_ptr[r];
    const int end = row_ptr[r + 1];
    const int deg = end - beg;

    int fi = beg + t16; if (fi > nnzT - 1) fi = nnzT - 1;
    const unsigned long long my = __builtin_nontemporal_load(&csr[fi]);

    const int m = deg < 16 ? deg : 16;
    const int gbase = g << 4;
    float acc[8] = {0.f, 0.f, 0.f, 0.f, 0.f, 0.f, 0.f, 0.f};

    bf16x8 hv[8]; float vv[8];
    // ---- batch 1: edges 0..7, loads issued back-to-back before any use ----
#pragma unroll
    for (int j = 0; j < 8; ++j) {
        if (j < m) {
            unsigned long long pv = __shfl(my, gbase + j);
            vv[j] = __uint_as_float((unsigned)(pv >> 32));
            hv[j] = *(const bf16x8*)(h + (long)(unsigned)(pv & 0xffffffffu) * CDIM + (t16 << 3));
        }
    }
#pragma unroll
    for (int j = 0; j < 8; ++j) {
        if (j < m) {
            union { bf16x8 v; unsigned u[4]; } H; H.v = hv[j];
#pragma unroll
            for (int d = 0; d < 4; ++d) {
                acc[2 * d]     += vv[j] * __uint_as_float(H.u[d] << 16);
                acc[2 * d + 1] += vv[j] * __uint_as_float(H.u[d] & 0xffff0000u);
            }
        }
    }
    // ---- batch 2: edges 8..15 (rare) ----
    if (__any(m > 8)) {
#pragma unroll
        for (int j = 8; j < 16; ++j) {
            if (j < m) {
                unsigned long long pv = __shfl(my, gbase + j);
                vv[j - 8] = __uint_as_float((unsigned)(pv >> 32));
                hv[j - 8] = *(const bf16x8*)(h + (long)(unsigned)(pv & 0xffffffffu) * CDIM + (t16 << 3));
            }
        }
#pragma unroll
        for (int j = 8; j < 16; ++j) {
            if (j < m) {
                union { bf16x8 v; unsigned u[4]; } H; H.v = hv[j - 8];
#pragma unroll
                for (int d = 0; d < 4; ++d) {
                    acc[2 * d]     += vv[j - 8] * __uint_as_float(H.u[d] << 16);
                    acc[2 * d + 1] += vv[j - 8] * __uint_as_float(H.u[d] & 0xffff0000u);
                }
            }
        }
    }
    // ---- serial tail for deg > 16 (statistically ~never) ----
    for (int i = beg + 16; i < end; ++i) {
        const unsigned long long pv = csr[i];
        const float val = __uint_as_float((unsigned)(pv >> 32));
        union { bf16x8 v; unsigned u[4]; } H;
        H.v = *(const bf16x8*)(h + (long)(unsigned)(pv & 0xffffffffu) * CDIM + (t16 << 3));
#pragma unroll
        for (int d = 0; d < 4; ++d) {
            acc[2 * d]     += val * __uint_as_float(H.u[d] << 16);
            acc[2 * d + 1] += val * __uint_as_float(H.u[d] & 0xffff0000u);
        }
    }

    f32x4 o0, o1;
#pragma unroll
    for (int j = 0; j < 4; ++j) {
        o0[j] = 1.0f / (1.0f + __expf(-acc[j]));
        o1[j] = 1.0f / (1.0f + __expf(-acc[4 + j]));
    }
    float* __restrict__ orow = out + (long)r * CDIM + (t16 << 3);
    __builtin_nontemporal_store(o0, (f32x4*)orow);
    __builtin_nontemporal_store(o1, (f32x4*)(orow + 4));
}

// ---------------- launch ----------------

extern "C" void kernel_launch(void* const* d_in, const int* in_sizes, int n_in,
                              void* d_out, int out_size, void* d_ws, size_t ws_size,
                              hipStream_t stream) {
    const float* x0 = (const float*)d_in[0];
    const float* x1 = (const float*)d_in[1];
    const float* W1 = (const float*)d_in[3];
    const float* W2 = (const float*)d_in[4];
    const int*   b1r = (const int*)d_in[5];
    const int*   b1c = (const int*)d_in[6];
    const float* b1v = (const float*)d_in[7];
    const int*   b2r = (const int*)d_in[8];
    const int*   b2c = (const int*)d_in[9];
    const float* b2v = (const float*)d_in[10];
    const int nnz1 = in_sizes[5];
    const int nnz2 = in_sizes[8];
    const int n0 = in_sizes[0] / CDIM;   // 100000
    const int n1 = in_sizes[1] / CDIM;   // 400000 (x1 rows = out1 rows)
    const int n2 = in_sizes[2] / CDIM;   // 300000
    const int N  = n1 + n2;              // combined dest space
    const int nnzT = nnz1 + nnz2;

    // workspace carve-up (ints unless noted)
    int* counts  = (int*)d_ws;                 // N
    int* row_ptr = counts + N;                 // N+1
    int* rank    = row_ptr + N + 1;            // nnzT
    int* bsums   = rank + nnzT;                // 512
    size_t iofs = (size_t)2 * N + 1 + nnzT + 512;
    iofs = (iofs + 1) & ~(size_t)1;            // 8B align
    unsigned long long* csr = (unsigned long long*)((int*)d_ws + iofs);  // nnzT (8B each)
    short* h0 = (short*)(csr + nnzT);          // n0*128 bf16
    short* h1 = h0 + (size_t)n0 * CDIM;        // n1*128 bf16

    float* out = (float*)d_out;                // rows [0, N) x 128

    const int nchunks = (N + SCAN_CHUNK - 1) / SCAN_CHUNK;  // 342 <= 512

    zero_ints<<<1024, 256, 0, stream>>>(counts, N);
    hist_rank<<<2048, 256, 0, stream>>>(b1c, nnz1, b2c, nnz2, n1, counts, rank);
    scan_chunks<<<nchunks, 256, 0, stream>>>(counts, row_ptr, bsums, N);
    scan_finalize<<<nchunks, 256, 0, stream>>>(row_ptr, bsums, N, nnzT);
    scatter_both<<<2048, 256, 0, stream>>>(b1r, b1c, b1v, nnz1, b2r, b2c, b2v, nnz2,
                                           n1, row_ptr, rank, csr);

    const int t0 = n0 >> 4, t1 = n1 >> 4;
    gemm_all<<<2048, 256, 0, stream>>>(x0, W1, h0, t0, x1, W2, h1, t1, 416);

    agg_all<<<N >> 4, 256, 0, stream>>>(h0, h1, row_ptr, csr, out, n1, nnzT);
}

// Round 16
// 388.358 us; speedup vs baseline: 1.1924x; 1.0016x over previous
//
#include <hip/hip_runtime.h>
#include <hip/hip_bf16.h>

#define CDIM 128
#define SCAN_CHUNK 2048   // elements per scan block (256 thr x 8); = 1<<11

typedef __attribute__((ext_vector_type(4))) float f32x4;
typedef __attribute__((ext_vector_type(8))) short bf16x8;
typedef __attribute__((ext_vector_type(4))) short bf16x4;

// RNE f32->bf16
__device__ __forceinline__ short f2bf(float f) {
    unsigned u = __float_as_uint(f);
    u += 0x7FFFu + ((u >> 16) & 1u);
    return (short)(u >> 16);
}

// ---------------- CSR build ----------------

__global__ __launch_bounds__(256) void zero_ints(int* __restrict__ p, int n) {
    int i = blockIdx.x * 256 + threadIdx.x;
    for (; i < n; i += gridDim.x * 256) p[i] = 0;
}

// histogram + per-edge rank within destination (atomicAdd return value)
__global__ __launch_bounds__(256) void hist_rank(
    const int* __restrict__ c1, int nnz1, const int* __restrict__ c2, int nnz2,
    int n1, int* __restrict__ counts, int* __restrict__ rank)
{
    const int gtid = blockIdx.x * 256 + threadIdx.x;
    const int gstride = gridDim.x * 256;
    for (int e = gtid; e < nnz1; e += gstride)
        rank[e] = atomicAdd(&counts[c1[e]], 1);
    for (int e = gtid; e < nnz2; e += gstride)
        rank[nnz1 + e] = atomicAdd(&counts[n1 + c2[e]], 1);
}

// per-chunk exclusive scan (chunk-LOCAL); chunk total -> bsums[chunk]
__global__ __launch_bounds__(256) void scan_chunks(const int* __restrict__ in, int* __restrict__ out,
                                                   int* __restrict__ bsums, int n) {
    __shared__ int wtot[4];
    const int t = threadIdx.x;
    const int base = blockIdx.x * SCAN_CHUNK + t * 8;
    int v[8]; int s = 0;
#pragma unroll
    for (int j = 0; j < 8; ++j) {
        int c = (base + j < n) ? in[base + j] : 0;
        v[j] = s; s += c;
    }
    const int lane = t & 63, w = t >> 6;
    int inc = s;
#pragma unroll
    for (int d = 1; d < 64; d <<= 1) {
        int o = __shfl_up(inc, d);
        if (lane >= d) inc += o;
    }
    if (lane == 63) wtot[w] = inc;
    __syncthreads();
    int off = inc - s;
    for (int i = 0; i < w; ++i) off += wtot[i];
#pragma unroll
    for (int j = 0; j < 8; ++j)
        if (base + j < n) out[base + j] = v[j] + off;
    if (t == 255) bsums[blockIdx.x] = off + s;
}

// single-block exclusive scan of bsums in place (nchunks <= 512)
__global__ __launch_bounds__(512) void scan_bsums(int* __restrict__ bsums, int nchunks) {
    __shared__ int sm[512];
    const int t = threadIdx.x;
    const int v = (t < nchunks) ? bsums[t] : 0;
    sm[t] = v;
    __syncthreads();
    for (int d = 1; d < 512; d <<= 1) {
        int add = (t >= d) ? sm[t - d] : 0;
        __syncthreads();
        sm[t] += add;
        __syncthreads();
    }
    if (t < nchunks) bsums[t] = sm[t] - v;   // exclusive prefix
}

// atomic-free scatter: pos = raw_row_ptr[dest] + bpre[dest>>11] + rank[e]
__global__ __launch_bounds__(256) void scatter_both(
    const int* __restrict__ r1, const int* __restrict__ c1, const float* __restrict__ v1, int nnz1,
    const int* __restrict__ r2, const int* __restrict__ c2, const float* __restrict__ v2, int nnz2,
    int n1, const int* __restrict__ row_ptr, const int* __restrict__ bpre,
    const int* __restrict__ rank, unsigned long long* __restrict__ csr)
{
    const int gtid = blockIdx.x * 256 + threadIdx.x;
    const int gstride = gridDim.x * 256;
    for (int e = gtid; e < nnz1; e += gstride) {
        const int d = c1[e];
        int p = row_ptr[d] + bpre[d >> 11] + rank[e];
        csr[p] = ((unsigned long long)__float_as_uint(__builtin_nontemporal_load(&v1[e])) << 32)
                 | (unsigned)__builtin_nontemporal_load(&r1[e]);
    }
    for (int e = gtid; e < nnz2; e += gstride) {
        const int d = n1 + c2[e];
        int p = row_ptr[d] + bpre[d >> 11] + rank[nnz1 + e];
        csr[p] = ((unsigned long long)__float_as_uint(__builtin_nontemporal_load(&v2[e])) << 32)
                 | (unsigned)__builtin_nontemporal_load(&r2[e]);
    }
}

// ---------------- dense GEMM: h = bf16(x @ W), both inputs in one launch ----------------
// Cross-iteration prefetch: next tile's 8 NT x-loads issue BEFORE the current
// tile's convert/MFMA/store -> ~1 load-latency exposure per wave.
__global__ __launch_bounds__(256) void gemm_all(
    const float* __restrict__ x0, const float* __restrict__ W1, short* __restrict__ h0, int t0,
    const float* __restrict__ x1, const float* __restrict__ W2, short* __restrict__ h1, int t1,
    int g0)
{
    const float* __restrict__ x; const float* __restrict__ W; short* __restrict__ h;
    int ntiles, bidx, nblk;
    if ((int)blockIdx.x < g0) { x = x0; W = W1; h = h0; ntiles = t0; bidx = blockIdx.x;       nblk = g0; }
    else                      { x = x1; W = W2; h = h1; ntiles = t1; bidx = blockIdx.x - g0; nblk = gridDim.x - g0; }

    __shared__ short Bfrag[4][8][64][8];   // [kk][nb][lane][j] = 32 KB, lane-linear 16B slots
    for (int slot = threadIdx.x; slot < 2048; slot += 256) {
        const int lane = slot & 63, nb = (slot >> 6) & 7, kk = slot >> 9;
        const int n  = nb * 16 + (lane & 15);
        const int k0 = kk * 32 + (lane >> 4) * 8;
        union { bf16x8 v; short s[8]; } f;
#pragma unroll
        for (int j = 0; j < 8; ++j) f.s[j] = f2bf(W[(k0 + j) * CDIM + n]);
        *(bf16x8*)&Bfrag[kk][nb][lane][0] = f.v;
    }
    __syncthreads();

    const int lane = threadIdx.x & 63;
    const int wid  = threadIdx.x >> 6;
    const int l15  = lane & 15;
    const int l4   = lane >> 4;
    const int stride = nblk * 4;

    int tile = bidx * 4 + wid;
    if (tile >= ntiles) return;

    f32x4 cur[8];
    {
        const float* __restrict__ p = x + (long)((tile << 4) + l15) * CDIM + (l4 << 3);
#pragma unroll
        for (int q = 0; q < 4; ++q) {
            cur[2 * q]     = __builtin_nontemporal_load((const f32x4*)(p + q * 32));
            cur[2 * q + 1] = __builtin_nontemporal_load((const f32x4*)(p + q * 32 + 4));
        }
    }

    for (;;) {
        const int nxt_tile = tile + stride;
        const bool has = nxt_tile < ntiles;
        f32x4 nxt[8];
        {
            const int lt = has ? nxt_tile : tile;   // dummy reload (cache-hot) on last iter
            const float* __restrict__ p = x + (long)((lt << 4) + l15) * CDIM + (l4 << 3);
#pragma unroll
            for (int q = 0; q < 4; ++q) {
                nxt[2 * q]     = __builtin_nontemporal_load((const f32x4*)(p + q * 32));
                nxt[2 * q + 1] = __builtin_nontemporal_load((const f32x4*)(p + q * 32 + 4));
            }
        }

        union { bf16x8 v; short s[8]; } X[4];
#pragma unroll
        for (int kk = 0; kk < 4; ++kk)
#pragma unroll
            for (int j = 0; j < 4; ++j) {
                X[kk].s[j]     = f2bf(cur[2 * kk][j]);
                X[kk].s[4 + j] = f2bf(cur[2 * kk + 1][j]);
            }

        f32x4 c[8];
#pragma unroll
        for (int nb = 0; nb < 8; ++nb) c[nb] = (f32x4){0.f, 0.f, 0.f, 0.f};
#pragma unroll
        for (int kk = 0; kk < 4; ++kk)
#pragma unroll
            for (int nb = 0; nb < 8; ++nb)
                c[nb] = __builtin_amdgcn_mfma_f32_16x16x32_bf16(
                            *(const bf16x8*)&Bfrag[kk][nb][lane][0], X[kk].v, c[nb], 0, 0, 0);

        short* __restrict__ hr = h + (long)((tile << 4) + l15) * CDIM + (l4 << 2);
#pragma unroll
        for (int nb = 0; nb < 8; ++nb) {
            bf16x4 p;
#pragma unroll
            for (int ri = 0; ri < 4; ++ri) p[ri] = f2bf(c[nb][ri]);
            *(bf16x4*)(hr + (nb << 4)) = p;
        }

        if (!has) break;
        tile = nxt_tile;
#pragma unroll
        for (int q = 0; q < 8; ++q) cur[q] = nxt[q];
    }
}

// ---------------- gather-aggregate-sigmoid ----------------
// 16 lanes per dest row. Lane t16 fetches csr[beg+t16] (one load covers <=16
// edges). Batch-of-8 gathers issued back-to-back before any FMA.
// Segment bounds reconstructed as raw[i] + bpre[i>>11] (no finalize pass).
__global__ __launch_bounds__(256) void agg_all(
    const short* __restrict__ h0, const short* __restrict__ h1,
    const int* __restrict__ row_ptr, const int* __restrict__ bpre,
    const unsigned long long* __restrict__ csr,
    float* __restrict__ out, int n1, int N, int nnzT)
{
    const int lane = threadIdx.x & 63;
    const int wid  = threadIdx.x >> 6;
    const int g    = lane >> 4;
    const int t16  = lane & 15;
    const int r = blockIdx.x * 16 + wid * 4 + g;
    const short* __restrict__ h = (r < n1) ? h0 : h1;   // n1 % 16 == 0 -> block-uniform
    const int beg = row_ptr[r] + bpre[r >> 11];
    const int end = (r == N - 1) ? nnzT : (row_ptr[r + 1] + bpre[(r + 1) >> 11]);
    const int deg = end - beg;

    int fi = beg + t16; if (fi > nnzT - 1) fi = nnzT - 1;
    const unsigned long long my = __builtin_nontemporal_load(&csr[fi]);

    const int m = deg < 16 ? deg : 16;
    const int gbase = g << 4;
    float acc[8] = {0.f, 0.f, 0.f, 0.f, 0.f, 0.f, 0.f, 0.f};

    bf16x8 hv[8]; float vv[8];
    // ---- batch 1: edges 0..7, loads issued back-to-back before any use ----
#pragma unroll
    for (int j = 0; j < 8; ++j) {
        if (j < m) {
            unsigned long long pv = __shfl(my, gbase + j);
            vv[j] = __uint_as_float((unsigned)(pv >> 32));
            hv[j] = *(const bf16x8*)(h + (long)(unsigned)(pv & 0xffffffffu) * CDIM + (t16 << 3));
        }
    }
#pragma unroll
    for (int j = 0; j < 8; ++j) {
        if (j < m) {
            union { bf16x8 v; unsigned u[4]; } H; H.v = hv[j];
#pragma unroll
            for (int d = 0; d < 4; ++d) {
                acc[2 * d]     += vv[j] * __uint_as_float(H.u[d] << 16);
                acc[2 * d + 1] += vv[j] * __uint_as_float(H.u[d] & 0xffff0000u);
            }
        }
    }
    // ---- batch 2: edges 8..15 (rare) ----
    if (__any(m > 8)) {
#pragma unroll
        for (int j = 8; j < 16; ++j) {
            if (j < m) {
                unsigned long long pv = __shfl(my, gbase + j);
                vv[j - 8] = __uint_as_float((unsigned)(pv >> 32));
                hv[j - 8] = *(const bf16x8*)(h + (long)(unsigned)(pv & 0xffffffffu) * CDIM + (t16 << 3));
            }
        }
#pragma unroll
        for (int j = 8; j < 16; ++j) {
            if (j < m) {
                union { bf16x8 v; unsigned u[4]; } H; H.v = hv[j - 8];
#pragma unroll
                for (int d = 0; d < 4; ++d) {
                    acc[2 * d]     += vv[j - 8] * __uint_as_float(H.u[d] << 16);
                    acc[2 * d + 1] += vv[j - 8] * __uint_as_float(H.u[d] & 0xffff0000u);
                }
            }
        }
    }
    // ---- serial tail for deg > 16 (statistically ~never) ----
    for (int i = beg + 16; i < end; ++i) {
        const unsigned long long pv = csr[i];
        const float val = __uint_as_float((unsigned)(pv >> 32));
        union { bf16x8 v; unsigned u[4]; } H;
        H.v = *(const bf16x8*)(h + (long)(unsigned)(pv & 0xffffffffu) * CDIM + (t16 << 3));
#pragma unroll
        for (int d = 0; d < 4; ++d) {
            acc[2 * d]     += val * __uint_as_float(H.u[d] << 16);
            acc[2 * d + 1] += val * __uint_as_float(H.u[d] & 0xffff0000u);
        }
    }

    f32x4 o0, o1;
#pragma unroll
    for (int j = 0; j < 4; ++j) {
        o0[j] = 1.0f / (1.0f + __expf(-acc[j]));
        o1[j] = 1.0f / (1.0f + __expf(-acc[4 + j]));
    }
    float* __restrict__ orow = out + (long)r * CDIM + (t16 << 3);
    __builtin_nontemporal_store(o0, (f32x4*)orow);
    __builtin_nontemporal_store(o1, (f32x4*)(orow + 4));
}

// ---------------- launch ----------------

extern "C" void kernel_launch(void* const* d_in, const int* in_sizes, int n_in,
                              void* d_out, int out_size, void* d_ws, size_t ws_size,
                              hipStream_t stream) {
    const float* x0 = (const float*)d_in[0];
    const float* x1 = (const float*)d_in[1];
    const float* W1 = (const float*)d_in[3];
    const float* W2 = (const float*)d_in[4];
    const int*   b1r = (const int*)d_in[5];
    const int*   b1c = (const int*)d_in[6];
    const float* b1v = (const float*)d_in[7];
    const int*   b2r = (const int*)d_in[8];
    const int*   b2c = (const int*)d_in[9];
    const float* b2v = (const float*)d_in[10];
    const int nnz1 = in_sizes[5];
    const int nnz2 = in_sizes[8];
    const int n0 = in_sizes[0] / CDIM;   // 100000
    const int n1 = in_sizes[1] / CDIM;   // 400000 (x1 rows = out1 rows)
    const int n2 = in_sizes[2] / CDIM;   // 300000
    const int N  = n1 + n2;              // combined dest space
    const int nnzT = nnz1 + nnz2;

    // workspace carve-up (ints unless noted)
    int* counts  = (int*)d_ws;                 // N
    int* row_ptr = counts + N;                 // N+1 (raw chunk-local scan)
    int* rank    = row_ptr + N + 1;            // nnzT
    int* bsums   = rank + nnzT;                // 512 (becomes exclusive prefix)
    size_t iofs = (size_t)2 * N + 1 + nnzT + 512;
    iofs = (iofs + 1) & ~(size_t)1;            // 8B align
    unsigned long long* csr = (unsigned long long*)((int*)d_ws + iofs);  // nnzT (8B each)
    short* h0 = (short*)(csr + nnzT);          // n0*128 bf16
    short* h1 = h0 + (size_t)n0 * CDIM;        // n1*128 bf16

    float* out = (float*)d_out;                // rows [0, N) x 128

    const int nchunks = (N + SCAN_CHUNK - 1) / SCAN_CHUNK;  // 342 <= 512

    zero_ints<<<1024, 256, 0, stream>>>(counts, N);
    hist_rank<<<2048, 256, 0, stream>>>(b1c, nnz1, b2c, nnz2, n1, counts, rank);
    scan_chunks<<<nchunks, 256, 0, stream>>>(counts, row_ptr, bsums, N);
    scan_bsums<<<1, 512, 0, stream>>>(bsums, nchunks);
    scatter_both<<<2048, 256, 0, stream>>>(b1r, b1c, b1v, nnz1, b2r, b2c, b2v, nnz2,
                                           n1, row_ptr, bsums, rank, csr);

    const int t0 = n0 >> 4, t1 = n1 >> 4;
    gemm_all<<<2048, 256, 0, stream>>>(x0, W1, h0, t0, x1, W2, h1, t1, 416);

    agg_all<<<N >> 4, 256, 0, stream>>>(h0, h1, row_ptr, bsums, csr, out, n1, N, nnzT);
}